// Round 5
// baseline (121.574 us; speedup 1.0000x reference)
//
#include <hip/hip_runtime.h>
#include <stdint.h>

// Problem constants (CLUSTER_AMNT=1024, CLUSTER_SIZE=8, EMBED_DIM=128)
#define N_TOTAL 8192
#define EMBED   128
#define CSIZE   8
#define MARGIN  1.0f
#define BIGF    3.0e38f

#define SEGS         32
#define COLS_PER_SEG (N_TOTAL / SEGS)            // 256
#define STEP_COLS    32
#define STEPS        (COLS_PER_SEG / STEP_COLS)  // 8
#define RT           8                            // row-tiles per wave (128 rows)
#define ROWS_PER_BLK 512                          // 4 waves x 128
#define ROW_BLOCKS   (N_TOTAL / ROWS_PER_BLK)     // 16

typedef __attribute__((ext_vector_type(8))) short  short8;   // 8 bf16 (4 VGPRs)
typedef __attribute__((ext_vector_type(4))) float  floatx4;  // MFMA C/D

__device__ __forceinline__ unsigned short f2bf(float f) {
    union { float f; unsigned u; } v; v.f = f;
    unsigned u = v.u;
    unsigned r = u + 0x7FFFu + ((u >> 16) & 1u);  // RNE bf16
    return (unsigned short)(r >> 16);
}

__device__ __forceinline__ void gl_lds16(const void* g, void* l) {
    __builtin_amdgcn_global_load_lds(
        (const __attribute__((address_space(1))) void*)g,
        (__attribute__((address_space(3))) void*)l, 16, 0, 0);
}

// ---------------------------------------------------------------------------
// prep_pos: fused. 4 waves/block, one cluster per wave (wave-synchronous).
// fp32->bf16 cast-out, exact fp32 row norms, hard positive, negBits=+inf,
// zero the per-rowBlock done counters and out[0].
// ---------------------------------------------------------------------------
__global__ __launch_bounds__(256) void prep_pos_kernel(
        const float* __restrict__ emb,
        unsigned short* __restrict__ ebf,
        float* __restrict__ n2,
        float* __restrict__ ap,
        unsigned* __restrict__ negBits,
        unsigned* __restrict__ cnt,
        float* __restrict__ out) {
    __shared__ __align__(16) float ls[4][CSIZE][EMBED + 4];  // row stride 132
    int tid  = threadIdx.x;
    int w    = tid >> 6;
    int lane = tid & 63;
    int c    = blockIdx.x * 4 + w;

    const float4* base = (const float4*)(emb + (size_t)c * CSIZE * EMBED);
    float4 v[4];
#pragma unroll
    for (int i = 0; i < 4; ++i) v[i] = base[lane + i * 64];

#pragma unroll
    for (int i = 0; i < 4; ++i) {
        int elem = (lane + i * 64) * 4;
        int r = elem >> 7, k = elem & 127;
        *(float4*)&ls[w][r][k] = v[i];
    }

    ushort4* dst = (ushort4*)(ebf + (size_t)c * CSIZE * EMBED);
#pragma unroll
    for (int i = 0; i < 4; ++i) {
        ushort4 o;
        o.x = f2bf(v[i].x); o.y = f2bf(v[i].y);
        o.z = f2bf(v[i].z); o.w = f2bf(v[i].w);
        dst[lane + i * 64] = o;
    }

    int i8 = lane >> 3, j8 = lane & 7;
    float sq = 0.f, s2 = 0.f;
#pragma unroll 8
    for (int k4 = 0; k4 < EMBED / 4; ++k4) {
        float4 a = *(const float4*)&ls[w][i8][k4 * 4];
        float4 b = *(const float4*)&ls[w][j8][k4 * 4];
        float d0 = a.x - b.x, d1 = a.y - b.y, d2 = a.z - b.z, d3 = a.w - b.w;
        sq = fmaf(d0, d0, sq); sq = fmaf(d1, d1, sq);
        sq = fmaf(d2, d2, sq); sq = fmaf(d3, d3, sq);
        s2 = fmaf(a.x, a.x, s2); s2 = fmaf(a.y, a.y, s2);
        s2 = fmaf(a.z, a.z, s2); s2 = fmaf(a.w, a.w, s2);
    }
#pragma unroll
    for (int off = 1; off < 8; off <<= 1) sq = fmaxf(sq, __shfl_xor(sq, off));
    if (j8 == 0) {
        ap[c * CSIZE + i8] = sqrtf(sq);
        n2[c * CSIZE + i8] = s2;
    }
    if (lane < CSIZE) negBits[c * CSIZE + lane] = 0x7F800000u;  // +inf
    if (blockIdx.x == 0) {
        if (tid < ROW_BLOCKS) cnt[tid] = 0u;
        if (tid == 0) out[0] = 0.f;
    }
}

// ---------------------------------------------------------------------------
// neg: bf16 MFMA Gram. Wave owns 128 rows (8 row-tiles, A-frags in 128 VGPRs);
// block = 512 rows. B staged through TWO STATIC LDS buffers (bt0/bt1,
// global_load_lds w=16) with a 2-step-unrolled loop so alias analysis keeps
// the vmcnt drain at the barrier, not before the ds_reads. acc init =
// -0.5*n2_col so min(n2c-2G) == -2*max(acc). Per-rowBlock last-done block
// reduces its 512 loss terms and atomicAdds into out[0].
// ---------------------------------------------------------------------------
__global__ __launch_bounds__(256, 2) void neg_kernel(
        const unsigned short* __restrict__ ebf,
        const float* __restrict__ n2,
        const float* __restrict__ ap,
        unsigned* __restrict__ negBits,
        unsigned* __restrict__ cnt,
        float* __restrict__ out) {
    __shared__ __align__(16) unsigned char bt0[STEP_COLS * 256];  // 8 KB
    __shared__ __align__(16) unsigned char bt1[STEP_COLS * 256];  // 8 KB
    __shared__ float n2l[COLS_PER_SEG];                           // 1 KB
    int lane = threadIdx.x & 63;
    int w    = threadIdx.x >> 6;
    int quad = lane >> 4;
    int l16  = lane & 15;
    int rowBlock = blockIdx.x >> 5;            // 16 row blocks of 512 rows
    int seg      = blockIdx.x & (SEGS - 1);    // 32 segments of 256 cols
    int rowStrip = rowBlock * ROWS_PER_BLK + w * (RT * 16);
    int colBase0 = seg * COLS_PER_SEG;

    // per-segment n2 tile (scaled): in-loop reads are lgkmcnt-only
    n2l[threadIdx.x] = -0.5f * n2[colBase0 + threadIdx.x];

    // A fragments: 8 row-tiles x 4 K-chunks = 128 VGPRs. A[m=l16][k=quad*8+j+32c]
    short8 afrag[RT][4];
#pragma unroll
    for (int rt = 0; rt < RT; ++rt)
#pragma unroll
        for (int c = 0; c < 4; ++c)
            afrag[rt][c] = *(const short8*)(ebf +
                (size_t)(rowStrip + rt * 16 + l16) * EMBED + c * 32 + quad * 8);

    float mx[RT][4];  // running max of (G_ij - 0.5*n2_j)
#pragma unroll
    for (int rt = 0; rt < RT; ++rt)
#pragma unroll
        for (int r = 0; r < 4; ++r) mx[rt][r] = -BIGF;

    // staging geometry (per wave: 2 insts; si = w*2+i covers cols 4si..4si+3)
    const char* gbase = (const char*)ebf;
    int jl[2], chn[2];
#pragma unroll
    for (int i = 0; i < 2; ++i) {
        int si = w * 2 + i;
        jl[i]  = 4 * si + (lane >> 4);           // 0..31 local col
        chn[i] = (lane & 15) ^ (jl[i] & 15);     // xor-swizzled 16B chunk
    }

    // step body: consume `buf` tile t; optionally stage tile t+1 into `nbuf`
    auto process = [&](const unsigned char* buf, int t,
                       unsigned char* nbuf, bool doStage) {
        int colBase = colBase0 + t * STEP_COLS;
        float nh0 = n2l[t * STEP_COLS + l16];
        float nh1 = n2l[t * STEP_COLS + 16 + l16];
        short8 bf[4];
        // h=0 fragment reads first (ds_read in flight before prefetch issue)
#pragma unroll
        for (int c = 0; c < 4; ++c)
            bf[c] = *(const short8*)(buf +
                ((l16 << 8) | ((((c << 2) + quad) ^ l16) << 4)));
        if (doStage) {
#pragma unroll
            for (int i = 0; i < 2; ++i) {
                int si = w * 2 + i;
                const char* gp = gbase +
                    ((size_t)(colBase + STEP_COLS + jl[i]) << 8) + (chn[i] << 4);
                gl_lds16(gp, (char*)nbuf + (si << 10));
            }
        }
        int colB = colBase;
#pragma unroll
        for (int rt = 0; rt < RT; ++rt) {
            floatx4 acc = {nh0, nh0, nh0, nh0};
#pragma unroll
            for (int c = 0; c < 4; ++c)
                acc = __builtin_amdgcn_mfma_f32_16x16x32_bf16(
                    afrag[rt][c], bf[c], acc, 0, 0, 0);
            if (colB == rowStrip + rt * 16) {  // wave-uniform: diagonal tile
                bool skip = ((quad >> 1) == (l16 >> 3));  // same 8-cluster
#pragma unroll
                for (int r = 0; r < 4; ++r)
                    mx[rt][r] = fmaxf(mx[rt][r], skip ? -BIGF : acc[r]);
            } else {
#pragma unroll
                for (int r = 0; r < 4; ++r)
                    mx[rt][r] = fmaxf(mx[rt][r], acc[r]);
            }
        }
        // h=1
#pragma unroll
        for (int c = 0; c < 4; ++c)
            bf[c] = *(const short8*)(buf +
                (((16 + l16) << 8) | ((((c << 2) + quad) ^ l16) << 4)));
        colB = colBase + 16;
#pragma unroll
        for (int rt = 0; rt < RT; ++rt) {
            floatx4 acc = {nh1, nh1, nh1, nh1};
#pragma unroll
            for (int c = 0; c < 4; ++c)
                acc = __builtin_amdgcn_mfma_f32_16x16x32_bf16(
                    afrag[rt][c], bf[c], acc, 0, 0, 0);
            if (colB == rowStrip + rt * 16) {
                bool skip = ((quad >> 1) == (l16 >> 3));
#pragma unroll
                for (int r = 0; r < 4; ++r)
                    mx[rt][r] = fmaxf(mx[rt][r], skip ? -BIGF : acc[r]);
            } else {
#pragma unroll
                for (int r = 0; r < 4; ++r)
                    mx[rt][r] = fmaxf(mx[rt][r], acc[r]);
            }
        }
    };

    // prime buffer 0 with tile 0
#pragma unroll
    for (int i = 0; i < 2; ++i) {
        int si = w * 2 + i;
        const char* gp = gbase + ((size_t)(colBase0 + jl[i]) << 8) + (chn[i] << 4);
        gl_lds16(gp, (char*)bt0 + (si << 10));
    }
    __syncthreads();  // bt0 staged, n2l ready

#pragma unroll 1
    for (int tt = 0; tt < STEPS; tt += 2) {
        process(bt0, tt, bt1, true);                  // tt+1 <= 7 always
        __syncthreads();                              // bt1 ready; bt0 free
        process(bt1, tt + 1, bt0, tt + 2 < STEPS);
        __syncthreads();                              // bt0 ready; bt1 free
    }

    // reduce over 16 columns (lanes sharing quad), commit per-row min
#pragma unroll
    for (int rt = 0; rt < RT; ++rt) {
#pragma unroll
        for (int r = 0; r < 4; ++r) {
            float m = mx[rt][r];
#pragma unroll
            for (int off = 1; off < 16; off <<= 1)
                m = fmaxf(m, __shfl_xor(m, off));
            if (l16 == 0) {
                int row = rowStrip + rt * 16 + quad * 4 + r;
                float val = fmaxf(fmaf(-2.f, m, n2[row]), 0.f);  // n2r+n2c-2G
                atomicMin(&negBits[row], __float_as_uint(val));
            }
        }
    }

    // ---- per-rowBlock finalize: last of 32 segment blocks reduces 512 rows
    __syncthreads();
    __shared__ unsigned lastFlag;
    __shared__ float wsum[4];
    if (threadIdx.x == 0) {
        __threadfence();
        unsigned old = atomicAdd(&cnt[rowBlock], 1u);
        lastFlag = (old == SEGS - 1) ? 1u : 0u;
    }
    __syncthreads();
    if (lastFlag) {
        float s = 0.f;
#pragma unroll
        for (int i = 0; i < 2; ++i) {
            int row = rowBlock * ROWS_PER_BLK + i * 256 + threadIdx.x;
            unsigned u = atomicOr(&negBits[row], 0u);  // device-coherent read
            float an = sqrtf(__uint_as_float(u));
            s += fmaxf(ap[row] - an + MARGIN, 0.f);
        }
#pragma unroll
        for (int off = 1; off < 64; off <<= 1) s += __shfl_xor(s, off);
        if (lane == 0) wsum[w] = s;
        __syncthreads();
        if (threadIdx.x == 0)
            atomicAdd(out, (wsum[0] + wsum[1] + wsum[2] + wsum[3]) * (1.0f / N_TOTAL));
    }
}

extern "C" void kernel_launch(void* const* d_in, const int* in_sizes, int n_in,
                              void* d_out, int out_size, void* d_ws, size_t ws_size,
                              hipStream_t stream) {
    const float* emb = (const float*)d_in[0];
    float* out = (float*)d_out;

    char* ws = (char*)d_ws;
    unsigned short* ebf     = (unsigned short*)ws;                          // 2 MiB
    float*          n2      = (float*)(ws + 2 * 1024 * 1024);               // 32 KiB
    float*          ap      = (float*)(ws + 2 * 1024 * 1024 + 32 * 1024);   // 32 KiB
    unsigned*       negBits = (unsigned*)(ws + 2 * 1024 * 1024 + 64 * 1024);// 32 KiB
    unsigned*       cnt     = (unsigned*)(ws + 2 * 1024 * 1024 + 96 * 1024);

    prep_pos_kernel<<<N_TOTAL / CSIZE / 4, 256, 0, stream>>>(emb, ebf, n2, ap, negBits, cnt, out);
    neg_kernel<<<ROW_BLOCKS * SEGS, 256, 0, stream>>>(ebf, n2, ap, negBits, cnt, out);
}

// Round 6
// 101.686 us; speedup vs baseline: 1.1956x; 1.1956x over previous
//
#include <hip/hip_runtime.h>
#include <stdint.h>

// Problem constants (CLUSTER_AMNT=1024, CLUSTER_SIZE=8, EMBED_DIM=128)
#define N_TOTAL 8192
#define EMBED   128
#define CSIZE   8
#define MARGIN  1.0f
#define BIGF    3.0e38f

#define SEGS         32
#define COLS_PER_SEG (N_TOTAL / SEGS)            // 256
#define TILES        (COLS_PER_SEG / 16)         // 16 column tiles
#define RT           4                           // row-tiles per wave (64 rows)
#define ROWS_PER_BLK 256                         // 4 waves x 64
#define ROW_BLOCKS   (N_TOTAL / ROWS_PER_BLK)    // 32

typedef __attribute__((ext_vector_type(8))) short  short8;   // 8 bf16 (4 VGPRs)
typedef __attribute__((ext_vector_type(4))) float  floatx4;  // MFMA C/D

__device__ __forceinline__ unsigned short f2bf(float f) {
    union { float f; unsigned u; } v; v.f = f;
    unsigned u = v.u;
    unsigned r = u + 0x7FFFu + ((u >> 16) & 1u);  // RNE bf16
    return (unsigned short)(r >> 16);
}

__device__ __forceinline__ void gl_lds16(const void* g, void* l) {
    __builtin_amdgcn_global_load_lds(
        (const __attribute__((address_space(1))) void*)g,
        (__attribute__((address_space(3))) void*)l, 16, 0, 0);
}

// ---------------------------------------------------------------------------
// prep_pos: fused. 4 waves/block, one cluster per wave (wave-synchronous).
// fp32->bf16 cast-out, exact fp32 row norms, hard positive, negBits=+inf,
// zero the per-rowBlock done counters and out[0].
// ---------------------------------------------------------------------------
__global__ __launch_bounds__(256) void prep_pos_kernel(
        const float* __restrict__ emb,
        unsigned short* __restrict__ ebf,
        float* __restrict__ n2,
        float* __restrict__ ap,
        unsigned* __restrict__ negBits,
        unsigned* __restrict__ cnt,
        float* __restrict__ out) {
    __shared__ __align__(16) float ls[4][CSIZE][EMBED + 4];  // row stride 132
    int tid  = threadIdx.x;
    int w    = tid >> 6;
    int lane = tid & 63;
    int c    = blockIdx.x * 4 + w;

    const float4* base = (const float4*)(emb + (size_t)c * CSIZE * EMBED);
    float4 v[4];
#pragma unroll
    for (int i = 0; i < 4; ++i) v[i] = base[lane + i * 64];

#pragma unroll
    for (int i = 0; i < 4; ++i) {
        int elem = (lane + i * 64) * 4;
        int r = elem >> 7, k = elem & 127;
        *(float4*)&ls[w][r][k] = v[i];
    }

    ushort4* dst = (ushort4*)(ebf + (size_t)c * CSIZE * EMBED);
#pragma unroll
    for (int i = 0; i < 4; ++i) {
        ushort4 o;
        o.x = f2bf(v[i].x); o.y = f2bf(v[i].y);
        o.z = f2bf(v[i].z); o.w = f2bf(v[i].w);
        dst[lane + i * 64] = o;
    }

    int i8 = lane >> 3, j8 = lane & 7;
    float sq = 0.f, s2 = 0.f;
#pragma unroll 8
    for (int k4 = 0; k4 < EMBED / 4; ++k4) {
        float4 a = *(const float4*)&ls[w][i8][k4 * 4];
        float4 b = *(const float4*)&ls[w][j8][k4 * 4];
        float d0 = a.x - b.x, d1 = a.y - b.y, d2 = a.z - b.z, d3 = a.w - b.w;
        sq = fmaf(d0, d0, sq); sq = fmaf(d1, d1, sq);
        sq = fmaf(d2, d2, sq); sq = fmaf(d3, d3, sq);
        s2 = fmaf(a.x, a.x, s2); s2 = fmaf(a.y, a.y, s2);
        s2 = fmaf(a.z, a.z, s2); s2 = fmaf(a.w, a.w, s2);
    }
#pragma unroll
    for (int off = 1; off < 8; off <<= 1) sq = fmaxf(sq, __shfl_xor(sq, off));
    if (j8 == 0) {
        ap[c * CSIZE + i8] = sqrtf(sq);
        n2[c * CSIZE + i8] = s2;
    }
    if (lane < CSIZE) negBits[c * CSIZE + lane] = 0x7F800000u;  // +inf
    if (blockIdx.x == 0) {
        if (tid < ROW_BLOCKS) cnt[tid] = 0u;
        if (tid == 0) out[0] = 0.f;
    }
}

// ---------------------------------------------------------------------------
// neg: bf16 MFMA Gram. The ENTIRE 256-column segment (64 KB bf16) is staged
// into LDS once (64x global_load_lds w=16), ONE barrier, then 16 column
// tiles of pure ds_read+MFMA with no barriers and no global traffic — no
// per-step vmcnt drain (the R3-R5 wall). LDS 65 KB -> 2 blocks/CU, so the
// compiler has no occupancy incentive to cap VGPRs (RT=4: ~150 regs, no
// spill). acc init = -0.5*n2_col so min(n2c-2G) == -2*max(acc).
// Per-rowBlock last-done block reduces its 256 loss terms into out[0].
// ---------------------------------------------------------------------------
__global__ __launch_bounds__(256, 2) void neg_kernel(
        const unsigned short* __restrict__ ebf,
        const float* __restrict__ n2,
        const float* __restrict__ ap,
        unsigned* __restrict__ negBits,
        unsigned* __restrict__ cnt,
        float* __restrict__ out) {
    __shared__ __align__(16) unsigned char btile[COLS_PER_SEG * 256];  // 64 KB
    __shared__ float n2l[COLS_PER_SEG];                                // 1 KB
    int lane = threadIdx.x & 63;
    int w    = threadIdx.x >> 6;
    int quad = lane >> 4;
    int l16  = lane & 15;
    int rowBlock = blockIdx.x >> 5;            // 32 row blocks of 256 rows
    int seg      = blockIdx.x & (SEGS - 1);    // 32 segments of 256 cols
    int rowStrip = rowBlock * ROWS_PER_BLK + w * (RT * 16);
    int colBase0 = seg * COLS_PER_SEG;

    // ---- stage the whole segment: 16 insts/wave, 1 KB each ----
    // inst si covers local cols 4si..4si+3; lane -> col jl = 4si+(lane>>4),
    // 16B chunk chn = (lane&15)^(jl&15)  => LDS addr = jl*256 + chn*16
    const char* gbase = (const char*)ebf;
#pragma unroll
    for (int i = 0; i < 16; ++i) {
        int si  = w * 16 + i;
        int jl  = 4 * si + (lane >> 4);
        int chn = (lane & 15) ^ (jl & 15);
        const char* gp = gbase + ((size_t)(colBase0 + jl) << 8) + (chn << 4);
        gl_lds16(gp, (char*)btile + (si << 10));
    }
    n2l[threadIdx.x] = -0.5f * n2[colBase0 + threadIdx.x];

    // A fragments: 4 row-tiles x 4 K-chunks = 64 VGPRs. A[m=l16][k=quad*8+j+32c]
    short8 afrag[RT][4];
#pragma unroll
    for (int rt = 0; rt < RT; ++rt)
#pragma unroll
        for (int c = 0; c < 4; ++c)
            afrag[rt][c] = *(const short8*)(ebf +
                (size_t)(rowStrip + rt * 16 + l16) * EMBED + c * 32 + quad * 8);

    float mx[RT][4];  // running max of (G_ij - 0.5*n2_j)
#pragma unroll
    for (int rt = 0; rt < RT; ++rt)
#pragma unroll
        for (int r = 0; r < 4; ++r) mx[rt][r] = -BIGF;

    __syncthreads();  // btile + n2l staged (single drain of the whole kernel)

    // ---- barrier-free inner loop: 16 tiles x (4 ds_read_b128 + 16 MFMA) ----
#pragma unroll 2
    for (int t16 = 0; t16 < TILES; ++t16) {
        float nh = n2l[t16 * 16 + l16];
        short8 bf[4];
#pragma unroll
        for (int c = 0; c < 4; ++c)
            bf[c] = *(const short8*)(btile +
                (((t16 * 16 + l16) << 8) | ((((c << 2) + quad) ^ l16) << 4)));
        int colB = colBase0 + t16 * 16;
#pragma unroll
        for (int rt = 0; rt < RT; ++rt) {
            floatx4 acc = {nh, nh, nh, nh};
#pragma unroll
            for (int c = 0; c < 4; ++c)
                acc = __builtin_amdgcn_mfma_f32_16x16x32_bf16(
                    afrag[rt][c], bf[c], acc, 0, 0, 0);
            if (colB == rowStrip + rt * 16) {  // wave-uniform: diagonal tile
                bool skip = ((quad >> 1) == (l16 >> 3));  // same 8-cluster
#pragma unroll
                for (int r = 0; r < 4; ++r)
                    mx[rt][r] = fmaxf(mx[rt][r], skip ? -BIGF : acc[r]);
            } else {
#pragma unroll
                for (int r = 0; r < 4; ++r)
                    mx[rt][r] = fmaxf(mx[rt][r], acc[r]);
            }
        }
    }

    // reduce over 16 columns (lanes sharing quad), commit per-row min
#pragma unroll
    for (int rt = 0; rt < RT; ++rt) {
#pragma unroll
        for (int r = 0; r < 4; ++r) {
            float m = mx[rt][r];
#pragma unroll
            for (int off = 1; off < 16; off <<= 1)
                m = fmaxf(m, __shfl_xor(m, off));
            if (l16 == 0) {
                int row = rowStrip + rt * 16 + quad * 4 + r;
                float val = fmaxf(fmaf(-2.f, m, n2[row]), 0.f);  // n2r+n2c-2G
                atomicMin(&negBits[row], __float_as_uint(val));
            }
        }
    }

    // ---- per-rowBlock finalize: last of 32 segment blocks reduces 256 rows
    __syncthreads();
    __shared__ unsigned lastFlag;
    __shared__ float wsum[4];
    if (threadIdx.x == 0) {
        __threadfence();
        unsigned old = atomicAdd(&cnt[rowBlock], 1u);
        lastFlag = (old == SEGS - 1) ? 1u : 0u;
    }
    __syncthreads();
    if (lastFlag) {
        int row = rowBlock * ROWS_PER_BLK + threadIdx.x;
        unsigned u = atomicOr(&negBits[row], 0u);  // device-coherent read
        float an = sqrtf(__uint_as_float(u));
        float s  = fmaxf(ap[row] - an + MARGIN, 0.f);
#pragma unroll
        for (int off = 1; off < 64; off <<= 1) s += __shfl_xor(s, off);
        if (lane == 0) wsum[w] = s;
        __syncthreads();
        if (threadIdx.x == 0)
            atomicAdd(out, (wsum[0] + wsum[1] + wsum[2] + wsum[3]) * (1.0f / N_TOTAL));
    }
}

extern "C" void kernel_launch(void* const* d_in, const int* in_sizes, int n_in,
                              void* d_out, int out_size, void* d_ws, size_t ws_size,
                              hipStream_t stream) {
    const float* emb = (const float*)d_in[0];
    float* out = (float*)d_out;

    char* ws = (char*)d_ws;
    unsigned short* ebf     = (unsigned short*)ws;                          // 2 MiB
    float*          n2      = (float*)(ws + 2 * 1024 * 1024);               // 32 KiB
    float*          ap      = (float*)(ws + 2 * 1024 * 1024 + 32 * 1024);   // 32 KiB
    unsigned*       negBits = (unsigned*)(ws + 2 * 1024 * 1024 + 64 * 1024);// 32 KiB
    unsigned*       cnt     = (unsigned*)(ws + 2 * 1024 * 1024 + 96 * 1024);

    prep_pos_kernel<<<N_TOTAL / CSIZE / 4, 256, 0, stream>>>(emb, ebf, n2, ap, negBits, cnt, out);
    neg_kernel<<<ROW_BLOCKS * SEGS, 256, 0, stream>>>(ebf, n2, ap, negBits, cnt, out);
}

// Round 7
// 101.085 us; speedup vs baseline: 1.2027x; 1.0059x over previous
//
#include <hip/hip_runtime.h>
#include <stdint.h>

// Problem constants (CLUSTER_AMNT=1024, CLUSTER_SIZE=8, EMBED_DIM=128)
#define N_TOTAL 8192
#define EMBED   128
#define CSIZE   8
#define MARGIN  1.0f
#define BIGF    3.0e38f

#define SEGS         32
#define COLS_PER_SEG (N_TOTAL / SEGS)            // 256
#define TILES        (COLS_PER_SEG / 16)         // 16 column tiles
#define RT           4                           // row-tiles per wave (64 rows)
#define ROWS_PER_BLK 256                         // 4 waves x 64
#define ROW_BLOCKS   (N_TOTAL / ROWS_PER_BLK)    // 32

typedef __attribute__((ext_vector_type(8))) short  short8;   // 8 bf16 (4 VGPRs)
typedef __attribute__((ext_vector_type(4))) float  floatx4;  // MFMA C/D

__device__ __forceinline__ unsigned short f2bf(float f) {
    union { float f; unsigned u; } v; v.f = f;
    unsigned u = v.u;
    unsigned r = u + 0x7FFFu + ((u >> 16) & 1u);  // RNE bf16
    return (unsigned short)(r >> 16);
}

__device__ __forceinline__ void gl_lds16(const void* g, void* l) {
    __builtin_amdgcn_global_load_lds(
        (const __attribute__((address_space(1))) void*)g,
        (__attribute__((address_space(3))) void*)l, 16, 0, 0);
}

// ---------------------------------------------------------------------------
// prep_pos: fused. 4 waves/block, one cluster per wave (wave-synchronous).
// fp32->bf16 cast-out, exact fp32 row norms, hard positive, negBits=+inf,
// zero the per-rowBlock done counters and out[0].
// ---------------------------------------------------------------------------
__global__ __launch_bounds__(256) void prep_pos_kernel(
        const float* __restrict__ emb,
        unsigned short* __restrict__ ebf,
        float* __restrict__ n2,
        float* __restrict__ ap,
        unsigned* __restrict__ negBits,
        unsigned* __restrict__ cnt,
        float* __restrict__ out) {
    __shared__ __align__(16) float ls[4][CSIZE][EMBED + 4];  // row stride 132
    int tid  = threadIdx.x;
    int w    = tid >> 6;
    int lane = tid & 63;
    int c    = blockIdx.x * 4 + w;

    const float4* base = (const float4*)(emb + (size_t)c * CSIZE * EMBED);
    float4 v[4];
#pragma unroll
    for (int i = 0; i < 4; ++i) v[i] = base[lane + i * 64];

#pragma unroll
    for (int i = 0; i < 4; ++i) {
        int elem = (lane + i * 64) * 4;
        int r = elem >> 7, k = elem & 127;
        *(float4*)&ls[w][r][k] = v[i];
    }

    ushort4* dst = (ushort4*)(ebf + (size_t)c * CSIZE * EMBED);
#pragma unroll
    for (int i = 0; i < 4; ++i) {
        ushort4 o;
        o.x = f2bf(v[i].x); o.y = f2bf(v[i].y);
        o.z = f2bf(v[i].z); o.w = f2bf(v[i].w);
        dst[lane + i * 64] = o;
    }

    int i8 = lane >> 3, j8 = lane & 7;
    float sq = 0.f, s2 = 0.f;
#pragma unroll 8
    for (int k4 = 0; k4 < EMBED / 4; ++k4) {
        float4 a = *(const float4*)&ls[w][i8][k4 * 4];
        float4 b = *(const float4*)&ls[w][j8][k4 * 4];
        float d0 = a.x - b.x, d1 = a.y - b.y, d2 = a.z - b.z, d3 = a.w - b.w;
        sq = fmaf(d0, d0, sq); sq = fmaf(d1, d1, sq);
        sq = fmaf(d2, d2, sq); sq = fmaf(d3, d3, sq);
        s2 = fmaf(a.x, a.x, s2); s2 = fmaf(a.y, a.y, s2);
        s2 = fmaf(a.z, a.z, s2); s2 = fmaf(a.w, a.w, s2);
    }
#pragma unroll
    for (int off = 1; off < 8; off <<= 1) sq = fmaxf(sq, __shfl_xor(sq, off));
    if (j8 == 0) {
        ap[c * CSIZE + i8] = sqrtf(sq);
        n2[c * CSIZE + i8] = s2;
    }
    if (lane < CSIZE) negBits[c * CSIZE + lane] = 0x7F800000u;  // +inf
    if (blockIdx.x == 0) {
        if (tid < ROW_BLOCKS) cnt[tid] = 0u;
        if (tid == 0) out[0] = 0.f;
    }
}

// ---------------------------------------------------------------------------
// neg: bf16 MFMA Gram. Whole 256-col segment (64 KB) staged into LDS once,
// ONE barrier, then 16 barrier-free tiles of ds_read+MFMA.
// KEY FIX vs R6: amdgpu_waves_per_eu(2,2) PINS the occupancy target.
// __launch_bounds__(256,2) only sets the MIN (range [2,8]); the allocator
// shrank to 88 VGPRs chasing 5 waves/EU and spilled afrag to scratch
// (WRITE_SIZE=4.1MB, inner-loop scratch reloads at L2 latency = 48 us).
// Pinning [2,2] gives a 256-VGPR budget; ~160 live regs fit, no spill.
// acc init = -0.5*n2_col so min(n2c-2G) == -2*max(acc).
// ---------------------------------------------------------------------------
__global__ __attribute__((amdgpu_flat_work_group_size(256, 256),
                          amdgpu_waves_per_eu(2, 2)))
void neg_kernel(
        const unsigned short* __restrict__ ebf,
        const float* __restrict__ n2,
        const float* __restrict__ ap,
        unsigned* __restrict__ negBits,
        unsigned* __restrict__ cnt,
        float* __restrict__ out) {
    __shared__ __align__(16) unsigned char btile[COLS_PER_SEG * 256];  // 64 KB
    __shared__ float n2l[COLS_PER_SEG];                                // 1 KB
    int lane = threadIdx.x & 63;
    int w    = threadIdx.x >> 6;
    int quad = lane >> 4;
    int l16  = lane & 15;
    int rowBlock = blockIdx.x >> 5;            // 32 row blocks of 256 rows
    int seg      = blockIdx.x & (SEGS - 1);    // 32 segments of 256 cols
    int rowStrip = rowBlock * ROWS_PER_BLK + w * (RT * 16);
    int colBase0 = seg * COLS_PER_SEG;

    // ---- stage the whole segment: 16 insts/wave, 1 KB each ----
    // inst si covers local cols 4si..4si+3; lane -> col jl = 4si+(lane>>4),
    // 16B chunk chn = (lane&15)^(jl&15)  => LDS addr = jl*256 + chn*16
    const char* gbase = (const char*)ebf;
#pragma unroll
    for (int i = 0; i < 16; ++i) {
        int si  = w * 16 + i;
        int jl  = 4 * si + (lane >> 4);
        int chn = (lane & 15) ^ (jl & 15);
        const char* gp = gbase + ((size_t)(colBase0 + jl) << 8) + (chn << 4);
        gl_lds16(gp, (char*)btile + (si << 10));
    }
    n2l[threadIdx.x] = -0.5f * n2[colBase0 + threadIdx.x];

    // A fragments: 4 row-tiles x 4 K-chunks = 64 VGPRs. A[m=l16][k=quad*8+j+32c]
    short8 afrag[RT][4];
#pragma unroll
    for (int rt = 0; rt < RT; ++rt)
#pragma unroll
        for (int c = 0; c < 4; ++c)
            afrag[rt][c] = *(const short8*)(ebf +
                (size_t)(rowStrip + rt * 16 + l16) * EMBED + c * 32 + quad * 8);

    float mx[RT][4];  // running max of (G_ij - 0.5*n2_j)
#pragma unroll
    for (int rt = 0; rt < RT; ++rt)
#pragma unroll
        for (int r = 0; r < 4; ++r) mx[rt][r] = -BIGF;

    __syncthreads();  // btile + n2l staged (single drain of the whole kernel)

    // ---- barrier-free inner loop: 16 tiles x (4 ds_read_b128 + 16 MFMA) ----
#pragma unroll 2
    for (int t16 = 0; t16 < TILES; ++t16) {
        float nh = n2l[t16 * 16 + l16];
        short8 bf[4];
#pragma unroll
        for (int c = 0; c < 4; ++c)
            bf[c] = *(const short8*)(btile +
                (((t16 * 16 + l16) << 8) | ((((c << 2) + quad) ^ l16) << 4)));
        int colB = colBase0 + t16 * 16;
#pragma unroll
        for (int rt = 0; rt < RT; ++rt) {
            floatx4 acc = {nh, nh, nh, nh};
#pragma unroll
            for (int c = 0; c < 4; ++c)
                acc = __builtin_amdgcn_mfma_f32_16x16x32_bf16(
                    afrag[rt][c], bf[c], acc, 0, 0, 0);
            if (colB == rowStrip + rt * 16) {  // wave-uniform: diagonal tile
                bool skip = ((quad >> 1) == (l16 >> 3));  // same 8-cluster
#pragma unroll
                for (int r = 0; r < 4; ++r)
                    mx[rt][r] = fmaxf(mx[rt][r], skip ? -BIGF : acc[r]);
            } else {
#pragma unroll
                for (int r = 0; r < 4; ++r)
                    mx[rt][r] = fmaxf(mx[rt][r], acc[r]);
            }
        }
    }

    // reduce over 16 columns (lanes sharing quad), commit per-row min
#pragma unroll
    for (int rt = 0; rt < RT; ++rt) {
#pragma unroll
        for (int r = 0; r < 4; ++r) {
            float m = mx[rt][r];
#pragma unroll
            for (int off = 1; off < 16; off <<= 1)
                m = fmaxf(m, __shfl_xor(m, off));
            if (l16 == 0) {
                int row = rowStrip + rt * 16 + quad * 4 + r;
                float val = fmaxf(fmaf(-2.f, m, n2[row]), 0.f);  // n2r+n2c-2G
                atomicMin(&negBits[row], __float_as_uint(val));
            }
        }
    }

    // ---- per-rowBlock finalize: last of 32 segment blocks reduces 256 rows
    __syncthreads();
    __shared__ unsigned lastFlag;
    __shared__ float wsum[4];
    if (threadIdx.x == 0) {
        __threadfence();
        unsigned old = atomicAdd(&cnt[rowBlock], 1u);
        lastFlag = (old == SEGS - 1) ? 1u : 0u;
    }
    __syncthreads();
    if (lastFlag) {
        int row = rowBlock * ROWS_PER_BLK + threadIdx.x;
        unsigned u = atomicOr(&negBits[row], 0u);  // device-coherent read
        float an = sqrtf(__uint_as_float(u));
        float s  = fmaxf(ap[row] - an + MARGIN, 0.f);
#pragma unroll
        for (int off = 1; off < 64; off <<= 1) s += __shfl_xor(s, off);
        if (lane == 0) wsum[w] = s;
        __syncthreads();
        if (threadIdx.x == 0)
            atomicAdd(out, (wsum[0] + wsum[1] + wsum[2] + wsum[3]) * (1.0f / N_TOTAL));
    }
}

extern "C" void kernel_launch(void* const* d_in, const int* in_sizes, int n_in,
                              void* d_out, int out_size, void* d_ws, size_t ws_size,
                              hipStream_t stream) {
    const float* emb = (const float*)d_in[0];
    float* out = (float*)d_out;

    char* ws = (char*)d_ws;
    unsigned short* ebf     = (unsigned short*)ws;                          // 2 MiB
    float*          n2      = (float*)(ws + 2 * 1024 * 1024);               // 32 KiB
    float*          ap      = (float*)(ws + 2 * 1024 * 1024 + 32 * 1024);   // 32 KiB
    unsigned*       negBits = (unsigned*)(ws + 2 * 1024 * 1024 + 64 * 1024);// 32 KiB
    unsigned*       cnt     = (unsigned*)(ws + 2 * 1024 * 1024 + 96 * 1024);

    prep_pos_kernel<<<N_TOTAL / CSIZE / 4, 256, 0, stream>>>(emb, ebf, n2, ap, negBits, cnt, out);
    neg_kernel<<<ROW_BLOCKS * SEGS, 256, 0, stream>>>(ebf, n2, ap, negBits, cnt, out);
}